// Round 12
// baseline (74.932 us; speedup 1.0000x reference)
//
#include <hip/hip_runtime.h>
#include <math.h>

#define DIM   2048
#define NEXP  64
#define BM    64
#define TPB   512
#define BK    64
#define NCH   (DIM / BK)   // 32

typedef float f32x4  __attribute__((ext_vector_type(4)));
typedef short bf16x8 __attribute__((ext_vector_type(8)));
typedef unsigned short u16;

// ---- fp32 -> 3-term bf16 split (RNE). Error ~2^-26 relative: index-safe. ----
__device__ __forceinline__ u16 rne_bf16(float f) {
    union { float f; unsigned u; } v; v.f = f;
    unsigned u = v.u;
    u += 0x7fffu + ((u >> 16) & 1u);
    return (u16)(u >> 16);
}
__device__ __forceinline__ float bf2f(u16 h) {
    union { unsigned u; float f; } v; v.u = ((unsigned)h) << 16;
    return v.f;
}
__device__ __forceinline__ void split3(float x, u16& a, u16& b, u16& c) {
    a = rne_bf16(x);
    float r1 = x - bf2f(a);
    b = rne_bf16(r1);
    float r2 = r1 - bf2f(b);
    c = rne_bf16(r2);
}

// ---------------- Kernel 0: W -> 3 bf16 planes, MFMA-B-fragment-linear -------
// Layout (u16): wp[(kstep*4 + etile)*3 + plane][lane][8]
// fragment element: W[16*etile + (lane&15)][32*kstep + 8*(lane>>4) + i]
__global__ __launch_bounds__(256)
void wconv(const float* __restrict__ Wg, u16* __restrict__ wp) {
    const int G  = blockIdx.x * 256 + threadIdx.x;   // 0..16383
    const int l  = G & 63;
    const int r  = G >> 6;                           // kstep*4 + etile, 0..255
    const int ks = r >> 2, et = r & 3;
    const int ex = et * 16 + (l & 15);
    const int k  = ks * 32 + (l >> 4) * 8;
    const float* src = Wg + (size_t)ex * DIM + k;
    f32x4 v0 = *(const f32x4*)src;
    f32x4 v1 = *(const f32x4*)(src + 4);
    u16 h0[8], h1[8], h2[8];
#pragma unroll
    for (int i = 0; i < 8; ++i) {
        float xv = (i < 4) ? v0[i] : v1[i - 4];
        split3(xv, h0[i], h1[i], h2[i]);
    }
    u16* dst = wp + ((size_t)r * 3) * 512 + l * 8;
    *(bf16x8*)(dst)        = *(bf16x8*)h0;
    *(bf16x8*)(dst + 512)  = *(bf16x8*)h1;
    *(bf16x8*)(dst + 1024) = *(bf16x8*)h2;
}

// ---------------- Kernel 1: fused MFMA logits + softmax + top-2 + aux --------
// 64 tokens x 64 experts per block, 8 waves (4 tok-tiles x 2 e-halves).
// B (W planes) flows global -> 3 regs/wave -> double-buffered LDS -> b128
// reads; ONE barrier per chunk makes the prefetch structural. x streams
// per-lane from global in A-fragment shape with a 1-chunk register prefetch.
__global__ __launch_bounds__(TPB)
void router_main(const float* __restrict__ x, const u16* __restrict__ wp,
                 float* __restrict__ out, float* __restrict__ gCnt,
                 float* __restrict__ gPsum, int n_tokens) {
    __shared__ __align__(16) u16 bbuf[2][24][512];   // 48 KB: 24 frags/chunk
    __shared__ float ls[BM][NEXP + 1];
    __shared__ float cnt[NEXP];
    __shared__ float rs[BM];

    const int tid  = threadIdx.x;
    const int t0   = blockIdx.x * BM;
    const int lane = tid & 63;
    const int wid  = tid >> 6;       // 0..7
    const int wr   = wid >> 1;       // tok-tile 0..3
    const int wc   = wid & 1;        // expert half 0..1

    if (tid < NEXP) cnt[tid] = 0.f;

    f32x4 acc0 = {0.f, 0.f, 0.f, 0.f};   // e-tile 2*wc
    f32x4 acc1 = {0.f, 0.f, 0.f, 0.f};   // e-tile 2*wc+1

    // per-lane x source: row = own token (m = lane&15), k-offset 8*(lane>>4)
    const float* xsrc = x + (size_t)(t0 + 16 * wr + (lane & 15)) * DIM + 8 * (lane >> 4);

    f32x4 px0, px1, px2, px3;            // x(c) raw (single named set)
    bf16x8 pb0, pb1, pb2;                // staged B frags (3 per wave)

#define LOADX(C) do {                                                          \
        const float* p_ = xsrc + (C) * BK;                                     \
        px0 = *(const f32x4*)(p_);                                             \
        px1 = *(const f32x4*)(p_ + 4);                                         \
        px2 = *(const f32x4*)(p_ + 32);                                        \
        px3 = *(const f32x4*)(p_ + 36);                                        \
    } while (0)

#define LOADB(C) do {                                                          \
        const u16* p_ = wp + ((size_t)(C) * 24 + 3 * wid) * 512 + lane * 8;    \
        pb0 = *(const bf16x8*)(p_);                                            \
        pb1 = *(const bf16x8*)(p_ + 512);                                      \
        pb2 = *(const bf16x8*)(p_ + 1024);                                     \
    } while (0)

#define STAGEB(B) do {                                                         \
        *(bf16x8*)&bbuf[B][3 * wid + 0][lane * 8] = pb0;                       \
        *(bf16x8*)&bbuf[B][3 * wid + 1][lane * 8] = pb1;                       \
        *(bf16x8*)&bbuf[B][3 * wid + 2][lane * 8] = pb2;                       \
    } while (0)

    // prologue: B(0) staged, x(0) in regs
    LOADB(0);
    STAGEB(0);
    LOADX(0);
    __syncthreads();

    for (int c = 0; c < NCH; ++c) {
        const int cur = c & 1;
        // 1) issue next-chunk B loads (latency covered by compute below)
        if (c + 1 < NCH) LOADB(c + 1);
        // 2) split3 current x -> A fragments (consumes px*)
        bf16x8 A[2][3];
#pragma unroll
        for (int s = 0; s < 2; ++s) {
            u16 a_[8], b_[8], c_[8];
#pragma unroll
            for (int i = 0; i < 8; ++i) {
                float f = (s == 0) ? ((i < 4) ? px0[i] : px1[i - 4])
                                   : ((i < 4) ? px2[i] : px3[i - 4]);
                split3(f, a_[i], b_[i], c_[i]);
            }
            A[s][0] = *(bf16x8*)a_;
            A[s][1] = *(bf16x8*)b_;
            A[s][2] = *(bf16x8*)c_;
        }
        // 3) issue next-chunk x loads (consumed next iter, after the barrier)
        if (c + 1 < NCH) LOADX(c + 1);
        // 4) compute: per (s, e-tile) 3 b128 LDS reads + 6 MFMAs
#pragma unroll
        for (int s = 0; s < 2; ++s) {
            const int base0 = (s * 4 + 2 * wc) * 3;
            bf16x8 B00 = *(const bf16x8*)&bbuf[cur][base0 + 0][lane * 8];
            bf16x8 B01 = *(const bf16x8*)&bbuf[cur][base0 + 1][lane * 8];
            bf16x8 B02 = *(const bf16x8*)&bbuf[cur][base0 + 2][lane * 8];
            acc0 = __builtin_amdgcn_mfma_f32_16x16x32_bf16(A[s][0], B00, acc0, 0, 0, 0);
            acc0 = __builtin_amdgcn_mfma_f32_16x16x32_bf16(A[s][0], B01, acc0, 0, 0, 0);
            acc0 = __builtin_amdgcn_mfma_f32_16x16x32_bf16(A[s][1], B00, acc0, 0, 0, 0);
            acc0 = __builtin_amdgcn_mfma_f32_16x16x32_bf16(A[s][1], B01, acc0, 0, 0, 0);
            acc0 = __builtin_amdgcn_mfma_f32_16x16x32_bf16(A[s][0], B02, acc0, 0, 0, 0);
            acc0 = __builtin_amdgcn_mfma_f32_16x16x32_bf16(A[s][2], B00, acc0, 0, 0, 0);
            const int base1 = (s * 4 + 2 * wc + 1) * 3;
            bf16x8 B10 = *(const bf16x8*)&bbuf[cur][base1 + 0][lane * 8];
            bf16x8 B11 = *(const bf16x8*)&bbuf[cur][base1 + 1][lane * 8];
            bf16x8 B12 = *(const bf16x8*)&bbuf[cur][base1 + 2][lane * 8];
            acc1 = __builtin_amdgcn_mfma_f32_16x16x32_bf16(A[s][0], B10, acc1, 0, 0, 0);
            acc1 = __builtin_amdgcn_mfma_f32_16x16x32_bf16(A[s][0], B11, acc1, 0, 0, 0);
            acc1 = __builtin_amdgcn_mfma_f32_16x16x32_bf16(A[s][1], B10, acc1, 0, 0, 0);
            acc1 = __builtin_amdgcn_mfma_f32_16x16x32_bf16(A[s][1], B11, acc1, 0, 0, 0);
            acc1 = __builtin_amdgcn_mfma_f32_16x16x32_bf16(A[s][0], B12, acc1, 0, 0, 0);
            acc1 = __builtin_amdgcn_mfma_f32_16x16x32_bf16(A[s][2], B10, acc1, 0, 0, 0);
        }
        // 5) stage next-chunk B into the other buffer (loads now complete)
        if (c + 1 < NCH) STAGEB(cur ^ 1);
        __syncthreads();
    }
#undef LOADX
#undef LOADB
#undef STAGEB

    // ---- epilogue: logits -> LDS (C-layout: col=lane&15, row=4*(lane>>4)+reg)
    {
        const int m0 = 16 * wr + 4 * (lane >> 4);
        const int n0 = 32 * wc + (lane & 15);
#pragma unroll
        for (int r2 = 0; r2 < 4; ++r2) {
            ls[m0 + r2][n0]      = acc0[r2];
            ls[m0 + r2][n0 + 16] = acc1[r2];
        }
    }
    __syncthreads();

    // ---- per-token top-2 + softmax: 8 threads per token ----
    const int tok = tid >> 3;        // 0..63
    const int sub = tid & 7;
    float l8[8];
#pragma unroll
    for (int j = 0; j < 8; ++j) l8[j] = ls[tok][sub * 8 + j];
    float m1 = -1e30f, m2 = -1e30f;
    int   i1 = 0, i2 = 0;
#pragma unroll
    for (int j = 0; j < 8; ++j) {
        float v = l8[j]; int e = sub * 8 + j;
        if (v > m1)      { m2 = m1; i2 = i1; m1 = v; i1 = e; }
        else if (v > m2) { m2 = v; i2 = e; }
    }
#pragma unroll
    for (int off = 1; off < 8; off <<= 1) {
        float n1 = __shfl_xor(m1, off, 8); int j1 = __shfl_xor(i1, off, 8);
        float n2 = __shfl_xor(m2, off, 8); int j2 = __shfl_xor(i2, off, 8);
        bool fb = (m1 > n1) || (m1 == n1 && i1 < j1);   // ties: lower index
        float a1 = fb ? m1 : n1;  int ai = fb ? i1 : j1;
        float b1 = fb ? n1 : m1;  int bi = fb ? j1 : i1;
        float c2 = fb ? m2 : n2;  int ci = fb ? i2 : j2;
        bool bb = (b1 > c2) || (b1 == c2 && bi < ci);
        m1 = a1; i1 = ai;
        m2 = bb ? b1 : c2; i2 = bb ? bi : ci;
    }
    float psum = 0.f;
#pragma unroll
    for (int j = 0; j < 8; ++j) {
        float p = __expf(l8[j] - m1);
        psum += p;
        ls[tok][sub * 8 + j] = p;    // unnormalized probs for column sums
    }
#pragma unroll
    for (int off = 1; off < 8; off <<= 1) psum += __shfl_xor(psum, off, 8);
    const float inv = 1.f / psum;
    if (sub == 0) {
        rs[tok] = inv;
        const float p1 = inv;                     // exp(0)*inv
        const float p2 = __expf(m2 - m1) * inv;
        const float d  = p1 + p2 + 1e-8f;
        const int tg = t0 + tok;
        out[(size_t)tg * 2]     = (float)i1;
        out[(size_t)tg * 2 + 1] = (float)i2;
        out[(size_t)n_tokens * 2 + (size_t)tg * 2]     = p1 / d;
        out[(size_t)n_tokens * 2 + (size_t)tg * 2 + 1] = p2 / d;
        atomicAdd(&cnt[i1], 1.f);
        atomicAdd(&cnt[i2], 1.f);
    }
    __syncthreads();

    // ---- per-expert column sums + global accumulation ----
    if (tid < NEXP) {
        float cs = 0.f;
#pragma unroll 8
        for (int t = 0; t < BM; ++t) cs += ls[t][tid] * rs[t];
        atomicAdd(&gPsum[tid], cs);
        atomicAdd(&gCnt[tid], cnt[tid]);
    }
}

// ---------------- Kernel 2: final aux loss -----------------------------------
__global__ void router_aux(const float* __restrict__ gCnt,
                           const float* __restrict__ gPsum,
                           float* __restrict__ out, int n_tokens) {
    const int e = threadIdx.x;
    float f = gCnt[e] / (float)(n_tokens * 2);
    float P = gPsum[e] / (float)n_tokens;
    float v = f * P;
#pragma unroll
    for (int o = 32; o > 0; o >>= 1) v += __shfl_down(v, o);
    if (e == 0) out[(size_t)n_tokens * 4] = 64.f * v;
}

extern "C" void kernel_launch(void* const* d_in, const int* in_sizes, int n_in,
                              void* d_out, int out_size, void* d_ws, size_t ws_size,
                              hipStream_t stream) {
    const float* x  = (const float*)d_in[0];
    const float* Wg = (const float*)d_in[1];
    float* out = (float*)d_out;
    const int n_tokens = in_sizes[0] / DIM;   // 16384

    // ws layout: wplanes (256*3*512 u16 = 786 KB), then gCnt/gPsum
    u16*   wplanes = (u16*)d_ws;
    float* gCnt    = (float*)((char*)d_ws + 256 * 3 * 512 * sizeof(u16));
    float* gPsum   = gCnt + NEXP;

    hipMemsetAsync(gCnt, 0, 2 * NEXP * sizeof(float), stream);
    hipLaunchKernelGGL(wconv, dim3(64), dim3(256), 0, stream, Wg, wplanes);
    hipLaunchKernelGGL(router_main, dim3(n_tokens / BM), dim3(TPB), 0, stream,
                       x, wplanes, out, gCnt, gPsum, n_tokens);
    hipLaunchKernelGGL(router_aux, dim3(1), dim3(NEXP), 0, stream,
                       gCnt, gPsum, out, n_tokens);
}

// Round 13
// 64.964 us; speedup vs baseline: 1.1534x; 1.1534x over previous
//
#include <hip/hip_runtime.h>
#include <math.h>

#define DIM    2048
#define NEXP   64
#define TPB    512
#define TOKB   32        // tokens per block (2 wave-tiles of 16)
#define KSTEPS 16        // ksteps (K=32) per wave; 4 K-quarters cover K=2048

typedef float f32x4  __attribute__((ext_vector_type(4)));
typedef short bf16x8 __attribute__((ext_vector_type(8)));
typedef unsigned short u16;

#define MFMA __builtin_amdgcn_mfma_f32_16x16x32_bf16

// ---- fp32 -> 3-term bf16 split (RNE). Error ~2^-26 relative: index-safe. ----
__device__ __forceinline__ u16 rne_bf16(float f) {
    union { float f; unsigned u; } v; v.f = f;
    unsigned u = v.u;
    u += 0x7fffu + ((u >> 16) & 1u);
    return (u16)(u >> 16);
}
__device__ __forceinline__ float bf2f(u16 h) {
    union { unsigned u; float f; } v; v.u = ((unsigned)h) << 16;
    return v.f;
}
__device__ __forceinline__ void split3(float x, u16& a, u16& b, u16& c) {
    a = rne_bf16(x);
    float r1 = x - bf2f(a);
    b = rne_bf16(r1);
    float r2 = r1 - bf2f(b);
    c = rne_bf16(r2);
}

// ---------------- Kernel 0: W -> 3 bf16 planes, MFMA-B-fragment-linear -------
// Layout (u16): wp[(kstep*4 + etile)*3 + plane][lane][8]
// fragment element: W[16*etile + (lane&15)][32*kstep + 8*(lane>>4) + i]
__global__ __launch_bounds__(256)
void wconv(const float* __restrict__ Wg, u16* __restrict__ wp) {
    const int G  = blockIdx.x * 256 + threadIdx.x;   // 0..16383
    const int l  = G & 63;
    const int r  = G >> 6;                           // kstep*4 + etile, 0..255
    const int ks = r >> 2, et = r & 3;
    const int ex = et * 16 + (l & 15);
    const int k  = ks * 32 + (l >> 4) * 8;
    const float* src = Wg + (size_t)ex * DIM + k;
    f32x4 v0 = *(const f32x4*)src;
    f32x4 v1 = *(const f32x4*)(src + 4);
    u16 h0[8], h1[8], h2[8];
#pragma unroll
    for (int i = 0; i < 8; ++i) {
        float xv = (i < 4) ? v0[i] : v1[i - 4];
        split3(xv, h0[i], h1[i], h2[i]);
    }
    u16* dst = wp + ((size_t)r * 3) * 512 + l * 8;
    *(bf16x8*)(dst)        = *(bf16x8*)h0;
    *(bf16x8*)(dst + 512)  = *(bf16x8*)h1;
    *(bf16x8*)(dst + 1024) = *(bf16x8*)h2;
}

// ---------------- Kernel 1: fused MFMA logits + softmax + top-2 + aux --------
// 32 tokens per block, 8 waves = 2 tok-tiles x 4 K-quarters. Each wave is
// INDEPENDENT in the main loop: its 16 tokens x 64 experts x K=512, x frags
// straight from global (split3 ONCE per element), B frags from L2-hot wp,
// 24 MFMAs/kstep into 4 accs. No main-loop LDS or barriers: 4 waves/SIMD
// TLP hides latency. End: LDS-reduce K-quarters, then top-2/softmax/aux.
__global__ __launch_bounds__(TPB, 4)
void router_main(const float* __restrict__ x, const u16* __restrict__ wp,
                 float* __restrict__ out, float* __restrict__ gCnt,
                 float* __restrict__ gPsum, int n_tokens) {
    __shared__ __align__(16) float ls[2][4][16][68];   // [tt][kq][m][e] 34.8 KB
    __shared__ float cnt[NEXP];
    __shared__ float rs[TOKB];

    const int tid  = threadIdx.x;
    const int lane = tid & 63;
    const int wid  = tid >> 6;          // 0..7
    const int kq   = wid & 3;           // K-quarter
    const int tt   = wid >> 2;          // token-tile 0/1
    const int t0   = blockIdx.x * TOKB + tt * 16;

    if (tid < NEXP) cnt[tid] = 0.f;

    f32x4 acc0 = {0.f, 0.f, 0.f, 0.f};
    f32x4 acc1 = {0.f, 0.f, 0.f, 0.f};
    f32x4 acc2 = {0.f, 0.f, 0.f, 0.f};
    f32x4 acc3 = {0.f, 0.f, 0.f, 0.f};

    // A-fragment source: row = lane&15, k = 8*(lane>>4)+i  (verified layout)
    const float* xsrc = x + (size_t)(t0 + (lane & 15)) * DIM
                          + kq * (KSTEPS * 32) + 8 * (lane >> 4);
    const u16* wl = wp + (size_t)lane * 8;

#pragma unroll 2
    for (int t = 0; t < KSTEPS; ++t) {
        f32x4 px0 = *(const f32x4*)(xsrc + 32 * t);
        f32x4 px1 = *(const f32x4*)(xsrc + 32 * t + 4);
        u16 a_[8], b_[8], c_[8];
#pragma unroll
        for (int i = 0; i < 8; ++i) {
            float f = (i < 4) ? px0[i] : px1[i - 4];
            split3(f, a_[i], b_[i], c_[i]);
        }
        bf16x8 A0 = *(bf16x8*)a_;
        bf16x8 A1 = *(bf16x8*)b_;
        bf16x8 A2 = *(bf16x8*)c_;
        const int kstep = kq * KSTEPS + t;
        const u16* wk = wl + (size_t)kstep * 12 * 512;
#define ETILE(ACC, ET) do {                                                    \
        const u16* p_ = wk + (size_t)(ET) * 3 * 512;                           \
        bf16x8 B0 = *(const bf16x8*)(p_);                                      \
        bf16x8 B1 = *(const bf16x8*)(p_ + 512);                                \
        bf16x8 B2 = *(const bf16x8*)(p_ + 1024);                               \
        ACC = MFMA(A0, B0, ACC, 0, 0, 0);                                      \
        ACC = MFMA(A0, B1, ACC, 0, 0, 0);                                      \
        ACC = MFMA(A1, B0, ACC, 0, 0, 0);                                      \
        ACC = MFMA(A1, B1, ACC, 0, 0, 0);                                      \
        ACC = MFMA(A0, B2, ACC, 0, 0, 0);                                      \
        ACC = MFMA(A2, B0, ACC, 0, 0, 0);                                      \
    } while (0)
        ETILE(acc0, 0);
        ETILE(acc1, 1);
        ETILE(acc2, 2);
        ETILE(acc3, 3);
#undef ETILE
    }

    // ---- write per-wave partial logits (C layout: col=lane&15, row=4*(lane>>4)+r)
    {
        const int mr = 4 * (lane >> 4);
        const int e0 = lane & 15;
#pragma unroll
        for (int r = 0; r < 4; ++r) {
            ls[tt][kq][mr + r][e0]      = acc0[r];
            ls[tt][kq][mr + r][e0 + 16] = acc1[r];
            ls[tt][kq][mr + r][e0 + 32] = acc2[r];
            ls[tt][kq][mr + r][e0 + 48] = acc3[r];
        }
    }
    __syncthreads();

    // ---- reduce 4 K-quarters (512 threads, one f32x4 each) ----
    {
        const int rt = tid >> 8;            // token-half 0/1
        const int m  = (tid >> 4) & 15;
        const int e4 = (tid & 15) * 4;
        f32x4 v = *(const f32x4*)&ls[rt][0][m][e4];
        v = v + *(const f32x4*)&ls[rt][1][m][e4];
        v = v + *(const f32x4*)&ls[rt][2][m][e4];
        v = v + *(const f32x4*)&ls[rt][3][m][e4];
        *(f32x4*)&ls[rt][0][m][e4] = v;
    }
    __syncthreads();

    // ---- per-token top-2 + softmax: 16 threads per token ----
    const int tok = tid >> 4;           // 0..31
    const int sub = tid & 15;
    const int rt2 = tok >> 4, mm = tok & 15;
    float l4[4];
#pragma unroll
    for (int j = 0; j < 4; ++j) l4[j] = ls[rt2][0][mm][sub * 4 + j];
    float m1 = -1e30f, m2 = -1e30f;
    int   i1 = 0, i2 = 0;
#pragma unroll
    for (int j = 0; j < 4; ++j) {
        float v = l4[j]; int e = sub * 4 + j;
        if (v > m1)      { m2 = m1; i2 = i1; m1 = v; i1 = e; }
        else if (v > m2) { m2 = v; i2 = e; }
    }
#pragma unroll
    for (int off = 1; off < 16; off <<= 1) {
        float n1 = __shfl_xor(m1, off, 16); int j1 = __shfl_xor(i1, off, 16);
        float n2 = __shfl_xor(m2, off, 16); int j2 = __shfl_xor(i2, off, 16);
        bool fb = (m1 > n1) || (m1 == n1 && i1 < j1);   // ties: lower index
        float a1 = fb ? m1 : n1;  int ai = fb ? i1 : j1;
        float b1 = fb ? n1 : m1;  int bi = fb ? j1 : i1;
        float c2 = fb ? m2 : n2;  int ci = fb ? i2 : j2;
        bool bb = (b1 > c2) || (b1 == c2 && bi < ci);
        m1 = a1; i1 = ai;
        m2 = bb ? b1 : c2; i2 = bb ? bi : ci;
    }
    float psum = 0.f;
#pragma unroll
    for (int j = 0; j < 4; ++j) {
        float p = __expf(l4[j] - m1);
        psum += p;
        ls[rt2][0][mm][sub * 4 + j] = p;    // unnormalized probs
    }
#pragma unroll
    for (int off = 1; off < 16; off <<= 1) psum += __shfl_xor(psum, off, 16);
    const float inv = 1.f / psum;
    if (sub == 0) {
        rs[tok] = inv;
        const float p1 = inv;                     // exp(0)*inv
        const float p2 = __expf(m2 - m1) * inv;
        const float d  = p1 + p2 + 1e-8f;
        const int tg = blockIdx.x * TOKB + tok;
        out[(size_t)tg * 2]     = (float)i1;
        out[(size_t)tg * 2 + 1] = (float)i2;
        out[(size_t)n_tokens * 2 + (size_t)tg * 2]     = p1 / d;
        out[(size_t)n_tokens * 2 + (size_t)tg * 2 + 1] = p2 / d;
        atomicAdd(&cnt[i1], 1.f);
        atomicAdd(&cnt[i2], 1.f);
    }
    __syncthreads();

    // ---- per-expert column sums + global accumulation ----
    if (tid < NEXP) {
        float cs = 0.f;
#pragma unroll
        for (int t2 = 0; t2 < TOKB; ++t2)
            cs += ls[t2 >> 4][0][t2 & 15][tid] * rs[t2];
        atomicAdd(&gPsum[tid], cs);
        atomicAdd(&gCnt[tid], cnt[tid]);
    }
}

// ---------------- Kernel 2: final aux loss -----------------------------------
__global__ void router_aux(const float* __restrict__ gCnt,
                           const float* __restrict__ gPsum,
                           float* __restrict__ out, int n_tokens) {
    const int e = threadIdx.x;
    float f = gCnt[e] / (float)(n_tokens * 2);
    float P = gPsum[e] / (float)n_tokens;
    float v = f * P;
#pragma unroll
    for (int o = 32; o > 0; o >>= 1) v += __shfl_down(v, o);
    if (e == 0) out[(size_t)n_tokens * 4] = 64.f * v;
}

extern "C" void kernel_launch(void* const* d_in, const int* in_sizes, int n_in,
                              void* d_out, int out_size, void* d_ws, size_t ws_size,
                              hipStream_t stream) {
    const float* x  = (const float*)d_in[0];
    const float* Wg = (const float*)d_in[1];
    float* out = (float*)d_out;
    const int n_tokens = in_sizes[0] / DIM;   // 16384

    // ws layout: wplanes (256*3*512 u16 = 786 KB), then gCnt/gPsum
    u16*   wplanes = (u16*)d_ws;
    float* gCnt    = (float*)((char*)d_ws + 256 * 3 * 512 * sizeof(u16));
    float* gPsum   = gCnt + NEXP;

    hipMemsetAsync(gCnt, 0, 2 * NEXP * sizeof(float), stream);
    hipLaunchKernelGGL(wconv, dim3(64), dim3(256), 0, stream, Wg, wplanes);
    hipLaunchKernelGGL(router_main, dim3(n_tokens / TOKB), dim3(TPB), 0, stream,
                       x, wplanes, out, gCnt, gPsum, n_tokens);
    hipLaunchKernelGGL(router_aux, dim3(1), dim3(NEXP), 0, stream,
                       gCnt, gPsum, out, n_tokens);
}

// Round 14
// 63.875 us; speedup vs baseline: 1.1731x; 1.0171x over previous
//
#include <hip/hip_runtime.h>
#include <math.h>

#define DIM   2048
#define NEXP  64
#define TPB   256
#define TOKB  32         // tokens per block (2 wave-tiles of 16)
#define NKH   2          // K halves (1024 each)
#define NCH   32         // ksteps (K=32) per K-half

typedef float f32x4  __attribute__((ext_vector_type(4)));
typedef short bf16x8 __attribute__((ext_vector_type(8)));
typedef unsigned short u16;

#define MFMA __builtin_amdgcn_mfma_f32_16x16x32_bf16

// ---- fp32 -> 3-term bf16 split (RNE). Error ~2^-26 relative: index-safe. ----
__device__ __forceinline__ u16 rne_bf16(float f) {
    union { float f; unsigned u; } v; v.f = f;
    unsigned u = v.u;
    u += 0x7fffu + ((u >> 16) & 1u);
    return (u16)(u >> 16);
}
__device__ __forceinline__ float bf2f(u16 h) {
    union { unsigned u; float f; } v; v.u = ((unsigned)h) << 16;
    return v.f;
}
__device__ __forceinline__ void split3(float x, u16& a, u16& b, u16& c) {
    a = rne_bf16(x);
    float r1 = x - bf2f(a);
    b = rne_bf16(r1);
    float r2 = r1 - bf2f(b);
    c = rne_bf16(r2);
}

// global->LDS direct DMA: dest = uniform LDS base + lane*16B; src per-lane.
#if defined(__has_builtin)
#if __has_builtin(__builtin_amdgcn_global_load_lds)
#define HAVE_GLD 1
#endif
#endif
#ifdef HAVE_GLD
#define STAGE16(GP, LBASE, LANE) __builtin_amdgcn_global_load_lds(            \
        (const __attribute__((address_space(1))) unsigned*)(GP),              \
        (__attribute__((address_space(3))) unsigned*)(LBASE), 16, 0, 0)
#else
#define STAGE16(GP, LBASE, LANE)                                              \
        (*(bf16x8*)((u16*)(LBASE) + (size_t)(LANE) * 8) = *(const bf16x8*)(GP))
#endif

// ---------------- Kernel 0: W -> 3 bf16 planes, MFMA-B-fragment-linear -------
// Layout (u16): wp[(kstep*4 + etile)*3 + plane][lane][8]
// fragment element: W[16*etile + (lane&15)][32*kstep + 8*(lane>>4) + i]
__global__ __launch_bounds__(256)
void wconv(const float* __restrict__ Wg, u16* __restrict__ wp) {
    const int G  = blockIdx.x * 256 + threadIdx.x;   // 0..16383
    const int l  = G & 63;
    const int r  = G >> 6;                           // kstep*4 + etile, 0..255
    const int ks = r >> 2, et = r & 3;
    const int ex = et * 16 + (l & 15);
    const int k  = ks * 32 + (l >> 4) * 8;
    const float* src = Wg + (size_t)ex * DIM + k;
    f32x4 v0 = *(const f32x4*)src;
    f32x4 v1 = *(const f32x4*)(src + 4);
    u16 h0[8], h1[8], h2[8];
#pragma unroll
    for (int i = 0; i < 8; ++i) {
        float xv = (i < 4) ? v0[i] : v1[i - 4];
        split3(xv, h0[i], h1[i], h2[i]);
    }
    u16* dst = wp + ((size_t)r * 3) * 512 + l * 8;
    *(bf16x8*)(dst)        = *(bf16x8*)h0;
    *(bf16x8*)(dst + 512)  = *(bf16x8*)h1;
    *(bf16x8*)(dst + 1024) = *(bf16x8*)h2;
}

// ---------------- Kernel 1: fused MFMA logits + softmax + top-2 + aux --------
// 32 tokens/block, 4 waves = 2 tok-tiles x 2 K-halves; grid 512 = 2 blocks/CU.
// B flows global -> LDS via global_load_lds (NO VGPR roundtrip), double-
// buffered, one barrier per kstep; x per-lane direct in A-fragment shape.
__global__ __launch_bounds__(TPB, 2)
void router_main(const float* __restrict__ x, const u16* __restrict__ wp,
                 float* __restrict__ out, float* __restrict__ gCnt,
                 float* __restrict__ gPsum, int n_tokens) {
    __shared__ __align__(16) u16 bbuf[2][NKH][12][512];   // 49.2 KB
    __shared__ float ls[2][NKH][16][68];                  // 17.4 KB
    __shared__ float cnt[NEXP];
    __shared__ float rs[TOKB];

    const int tid  = threadIdx.x;
    const int lane = tid & 63;
    const int wid  = tid >> 6;       // 0..3
    const int kh   = wid & 1;        // K-half
    const int tt   = wid >> 1;       // token-tile 0/1
    const int t0   = blockIdx.x * TOKB + tt * 16;

    if (tid < NEXP) cnt[tid] = 0.f;

    f32x4 acc[4];
#pragma unroll
    for (int et = 0; et < 4; ++et) acc[et] = (f32x4){0.f, 0.f, 0.f, 0.f};

    // A-fragment source: row = lane&15, k = 8*(lane>>4)+i  (verified layout)
    const float* xsrc = x + (size_t)(t0 + (lane & 15)) * DIM
                          + kh * (NCH * 32) + 8 * (lane >> 4);

    // stage kstep 0 (wave stages frags [6*tt, 6*tt+6) of its kh)
#pragma unroll
    for (int f = 0; f < 6; ++f) {
        const int fr = 6 * tt + f;
        const u16* gp = wp + ((size_t)(kh * NCH + 0) * 12 + fr) * 512 + lane * 8;
        STAGE16(gp, &bbuf[0][kh][fr][0], lane);
    }
    f32x4 px0 = *(const f32x4*)(xsrc);
    f32x4 px1 = *(const f32x4*)(xsrc + 4);
    __syncthreads();

    for (int c = 0; c < NCH; ++c) {
        const int cur = c & 1;
        // split3 current x -> A fragments (consumes px)
        u16 a_[8], b_[8], c_[8];
#pragma unroll
        for (int i = 0; i < 8; ++i) {
            float f = (i < 4) ? px0[i] : px1[i - 4];
            split3(f, a_[i], b_[i], c_[i]);
        }
        bf16x8 A0 = *(bf16x8*)a_;
        bf16x8 A1 = *(bf16x8*)b_;
        bf16x8 A2 = *(bf16x8*)c_;
        // issue next x loads + next B DMA (latency hidden by compute below)
        if (c + 1 < NCH) {
            px0 = *(const f32x4*)(xsrc + (c + 1) * 32);
            px1 = *(const f32x4*)(xsrc + (c + 1) * 32 + 4);
#pragma unroll
            for (int f = 0; f < 6; ++f) {
                const int fr = 6 * tt + f;
                const u16* gp = wp + ((size_t)(kh * NCH + c + 1) * 12 + fr) * 512 + lane * 8;
                STAGE16(gp, &bbuf[cur ^ 1][kh][fr][0], lane);
            }
        }
        // compute: 12 ds_read_b128 + 24 MFMA
#pragma unroll
        for (int et = 0; et < 4; ++et) {
            bf16x8 B0 = *(const bf16x8*)&bbuf[cur][kh][et * 3 + 0][lane * 8];
            bf16x8 B1 = *(const bf16x8*)&bbuf[cur][kh][et * 3 + 1][lane * 8];
            bf16x8 B2 = *(const bf16x8*)&bbuf[cur][kh][et * 3 + 2][lane * 8];
            acc[et] = MFMA(A0, B0, acc[et], 0, 0, 0);
            acc[et] = MFMA(A0, B1, acc[et], 0, 0, 0);
            acc[et] = MFMA(A1, B0, acc[et], 0, 0, 0);
            acc[et] = MFMA(A1, B1, acc[et], 0, 0, 0);
            acc[et] = MFMA(A0, B2, acc[et], 0, 0, 0);
            acc[et] = MFMA(A2, B0, acc[et], 0, 0, 0);
        }
        __syncthreads();
    }

    // ---- per-wave partial logits (C layout: col=lane&15, row=4*(lane>>4)+r)
    {
        const int mr = 4 * (lane >> 4);
        const int e0 = lane & 15;
#pragma unroll
        for (int r = 0; r < 4; ++r) {
            ls[tt][kh][mr + r][e0]      = acc[0][r];
            ls[tt][kh][mr + r][e0 + 16] = acc[1][r];
            ls[tt][kh][mr + r][e0 + 32] = acc[2][r];
            ls[tt][kh][mr + r][e0 + 48] = acc[3][r];
        }
    }
    __syncthreads();

    // ---- reduce the 2 K-halves (256 threads x 2 f32x4) ----
#pragma unroll
    for (int r2 = 0; r2 < 2; ++r2) {
        const int idx = tid + 256 * r2;     // 0..511
        const int tk  = idx >> 4;           // 0..31
        const int e4  = (idx & 15) * 4;
        f32x4 v = *(const f32x4*)&ls[tk >> 4][0][tk & 15][e4];
        v = v + *(const f32x4*)&ls[tk >> 4][1][tk & 15][e4];
        *(f32x4*)&ls[tk >> 4][0][tk & 15][e4] = v;
    }
    __syncthreads();

    // ---- per-token top-2 + softmax: 8 threads per token ----
    const int tok = tid >> 3;           // 0..31
    const int sub = tid & 7;
    const int rt2 = tok >> 4, mm = tok & 15;
    float l8[8];
#pragma unroll
    for (int j = 0; j < 8; ++j) l8[j] = ls[rt2][0][mm][sub * 8 + j];
    float m1 = -1e30f, m2 = -1e30f;
    int   i1 = 0, i2 = 0;
#pragma unroll
    for (int j = 0; j < 8; ++j) {
        float v = l8[j]; int e = sub * 8 + j;
        if (v > m1)      { m2 = m1; i2 = i1; m1 = v; i1 = e; }
        else if (v > m2) { m2 = v; i2 = e; }
    }
#pragma unroll
    for (int off = 1; off < 8; off <<= 1) {
        float n1 = __shfl_xor(m1, off, 8); int j1 = __shfl_xor(i1, off, 8);
        float n2 = __shfl_xor(m2, off, 8); int j2 = __shfl_xor(i2, off, 8);
        bool fb = (m1 > n1) || (m1 == n1 && i1 < j1);   // ties: lower index
        float a1 = fb ? m1 : n1;  int ai = fb ? i1 : j1;
        float b1 = fb ? n1 : m1;  int bi = fb ? j1 : i1;
        float c2 = fb ? m2 : n2;  int ci = fb ? i2 : j2;
        bool bb = (b1 > c2) || (b1 == c2 && bi < ci);
        m1 = a1; i1 = ai;
        m2 = bb ? b1 : c2; i2 = bb ? bi : ci;
    }
    float psum = 0.f;
#pragma unroll
    for (int j = 0; j < 8; ++j) {
        float p = __expf(l8[j] - m1);
        psum += p;
        ls[rt2][0][mm][sub * 8 + j] = p;    // unnormalized probs
    }
#pragma unroll
    for (int off = 1; off < 8; off <<= 1) psum += __shfl_xor(psum, off, 8);
    const float inv = 1.f / psum;
    if (sub == 0) {
        rs[tok] = inv;
        const float p1 = inv;                     // exp(0)*inv
        const float p2 = __expf(m2 - m1) * inv;
        const float d  = p1 + p2 + 1e-8f;
        const int tg = blockIdx.x * TOKB + tok;
        out[(size_t)tg * 2]     = (float)i1;
        out[(size_t)tg * 2 + 1] = (float)i2;
        out[(size_t)n_tokens * 2 + (size_t)tg * 2]     = p1 / d;
        out[(size_t)n_tokens * 2 + (size_t)tg * 2 + 1] = p2 / d;
        atomicAdd(&cnt[i1], 1.f);
        atomicAdd(&cnt[i2], 1.f);
    }
    __syncthreads();

    // ---- per-expert column sums + global accumulation ----
    if (tid < NEXP) {
        float cs = 0.f;
#pragma unroll
        for (int t2 = 0; t2 < TOKB; ++t2)
            cs += ls[t2 >> 4][0][t2 & 15][tid] * rs[t2];
        atomicAdd(&gPsum[tid], cs);
        atomicAdd(&gCnt[tid], cnt[tid]);
    }
}

// ---------------- Kernel 2: final aux loss -----------------------------------
__global__ void router_aux(const float* __restrict__ gCnt,
                           const float* __restrict__ gPsum,
                           float* __restrict__ out, int n_tokens) {
    const int e = threadIdx.x;
    float f = gCnt[e] / (float)(n_tokens * 2);
    float P = gPsum[e] / (float)n_tokens;
    float v = f * P;
#pragma unroll
    for (int o = 32; o > 0; o >>= 1) v += __shfl_down(v, o);
    if (e == 0) out[(size_t)n_tokens * 4] = 64.f * v;
}

extern "C" void kernel_launch(void* const* d_in, const int* in_sizes, int n_in,
                              void* d_out, int out_size, void* d_ws, size_t ws_size,
                              hipStream_t stream) {
    const float* x  = (const float*)d_in[0];
    const float* Wg = (const float*)d_in[1];
    float* out = (float*)d_out;
    const int n_tokens = in_sizes[0] / DIM;   // 16384

    // ws layout: wplanes (256*3*512 u16 = 786 KB), then gCnt/gPsum
    u16*   wplanes = (u16*)d_ws;
    float* gCnt    = (float*)((char*)d_ws + 256 * 3 * 512 * sizeof(u16));
    float* gPsum   = gCnt + NEXP;

    hipMemsetAsync(gCnt, 0, 2 * NEXP * sizeof(float), stream);
    hipLaunchKernelGGL(wconv, dim3(64), dim3(256), 0, stream, Wg, wplanes);
    hipLaunchKernelGGL(router_main, dim3(n_tokens / TOKB), dim3(TPB), 0, stream,
                       x, wplanes, out, gCnt, gPsum, n_tokens);
    hipLaunchKernelGGL(router_aux, dim3(1), dim3(NEXP), 0, stream,
                       gCnt, gPsum, out, n_tokens);
}